// Round 4
// baseline (39.778 us; speedup 1.0000x reference)
//
#include <hip/hip_runtime.h>

// Reference uses ONLY the last input channel (CIN-1) and matching weight slice:
// out[b,co,h,w] = bias[co] + sum_{kh,kw} x[b,63,h+kh,w+kw] * wt[co,63,kh,kw]
// Shapes: x (64,64,114,114) f32, wt (64,64,3,3) f32, bias (64) f32,
//         out (64,64,112,112) f32 (205.5 MB) -> write-BW bound, floor ~30us
// (harness fill kernel measures 7.0 TB/s write => 29.4us pure-write floor).

#define CB    64
#define CCIN  64
#define CCOUT 64
#define CH    112
#define CW    112
#define CHP   114
#define CWP   114
#define NCO   4               // co values per thread (x-data reuse)
#define SPT   (CH * (CW/4))   // 3136 spatial float4-groups per (b,co) plane

typedef float v4f __attribute__((ext_vector_type(4)));  // native vec for nt-store

__global__ __launch_bounds__(256) void CustomConv2D_12953621365171_kernel(
    const float* __restrict__ x,      // (B, CIN, 114, 114)
    const float* __restrict__ wt,     // (COUT, CIN, 3, 3)
    const float* __restrict__ bias,   // (COUT,)
    float* __restrict__ out)          // (B, COUT, 112, 112)
{
    int s = blockIdx.x * 256 + threadIdx.x;       // spatial: h*28 + wv
    if (s >= SPT) return;
    const int co0 = blockIdx.y * NCO;             // block-uniform -> SGPR
    const int b   = blockIdx.z;                   // block-uniform -> SGPR

    int h  = s / 28;                              // 32-bit magic-mul div
    int wv = s - h * 28;
    int w0 = wv * 4;

    // channel-63 x slice for this batch (uniform base + per-lane offset)
    const float* xs = x + ((size_t)b * CCIN + (CCIN - 1)) * (CHP * CWP);

    // Weights & bias: addresses depend only on blockIdx -> scalar loads
    float wk[NCO][9];
    float bv[NCO];
    #pragma unroll
    for (int j = 0; j < NCO; ++j) {
        const float* wp = wt + ((size_t)(co0 + j) * CCIN + (CCIN - 1)) * 9;
        #pragma unroll
        for (int t = 0; t < 9; ++t) wk[j][t] = wp[t];
        bv[j] = bias[co0 + j];
    }

    // Load the 3 input rows with wide loads: 24B memcpy lets the compiler emit
    // dwordx4+dwordx2 (or dwordx2 x3) instead of 6 scalar dword loads per row.
    float r[3][6];
    #pragma unroll
    for (int kh = 0; kh < 3; ++kh) {
        const float* row = xs + (h + kh) * CWP + w0;
        __builtin_memcpy(&r[kh][0], row, 6 * sizeof(float));
    }

    float acc[NCO][4];
    #pragma unroll
    for (int j = 0; j < NCO; ++j) {
        acc[j][0] = bv[j]; acc[j][1] = bv[j]; acc[j][2] = bv[j]; acc[j][3] = bv[j];
    }

    #pragma unroll
    for (int kh = 0; kh < 3; ++kh) {
        float r0 = r[kh][0], r1 = r[kh][1], r2 = r[kh][2];
        float r3 = r[kh][3], r4 = r[kh][4], r5 = r[kh][5];
        #pragma unroll
        for (int j = 0; j < NCO; ++j) {
            float k0 = wk[j][kh * 3 + 0];
            float k1 = wk[j][kh * 3 + 1];
            float k2 = wk[j][kh * 3 + 2];
            acc[j][0] = fmaf(k0, r0, fmaf(k1, r1, fmaf(k2, r2, acc[j][0])));
            acc[j][1] = fmaf(k0, r1, fmaf(k1, r2, fmaf(k2, r3, acc[j][1])));
            acc[j][2] = fmaf(k0, r2, fmaf(k1, r3, fmaf(k2, r4, acc[j][2])));
            acc[j][3] = fmaf(k0, r3, fmaf(k1, r4, fmaf(k2, r5, acc[j][3])));
        }
    }

    // out offset for (b, co0+j, h, w0) = plane*12544 + s*4 ; contiguous float4.
    // Non-temporal: output is write-once, never re-read -> evict-first in L2.
    #pragma unroll
    for (int j = 0; j < NCO; ++j) {
        v4f o = { acc[j][0], acc[j][1], acc[j][2], acc[j][3] };
        size_t off = ((size_t)b * CCOUT + (co0 + j)) * (CH * CW) + (size_t)s * 4;
        __builtin_nontemporal_store(o, reinterpret_cast<v4f*>(out + off));
    }
}

extern "C" void kernel_launch(void* const* d_in, const int* in_sizes, int n_in,
                              void* d_out, int out_size, void* d_ws, size_t ws_size,
                              hipStream_t stream) {
    const float* x    = (const float*)d_in[0];
    const float* wt   = (const float*)d_in[1];
    const float* bias = (const float*)d_in[2];
    float* out = (float*)d_out;

    dim3 grid((SPT + 255) / 256,      // 13
              CCOUT / NCO,            // 16
              CB);                    // 64
    dim3 block(256, 1, 1);

    CustomConv2D_12953621365171_kernel<<<grid, block, 0, stream>>>(x, wt, bias, out);
}